// Round 11
// baseline (1277.149 us; speedup 1.0000x reference)
//
#include <hip/hip_runtime.h>
#include <hip/hip_bf16.h>
#include <stdint.h>

typedef int v4i __attribute__((ext_vector_type(4)));

#define AS_GLOBAL(p) ((const __attribute__((address_space(1))) void*)(p))
#define AS_LDS(p)    ((__attribute__((address_space(3))) void*)(p))

// ---------------- merged prepass: rows [0,M) = x - izp (+rowsum); rows [M, M+N) = w - 128
__global__ __launch_bounds__(256) void prep_kernel(const int* __restrict__ x,
                                                   const int* __restrict__ w,
                                                   const int* __restrict__ izp_p,
                                                   signed char* __restrict__ xs,
                                                   signed char* __restrict__ wsq,
                                                   int* __restrict__ rowsum, int M, int K) {
    int row = blockIdx.x;
    int n4 = K >> 2;
    if (row < M) {
        int izp = izp_p[0];
        const int4* xr = (const int4*)(x + (long)row * K);
        uint32_t* xo = (uint32_t*)(xs + (long)row * K);
        int sum = 0;
        for (int i = threadIdx.x; i < n4; i += 256) {
            int4 v = xr[i];
            int a0 = v.x - izp, a1 = v.y - izp, a2 = v.z - izp, a3 = v.w - izp;
            sum += a0 + a1 + a2 + a3;
            xo[i] = (uint32_t)(a0 & 0xFF) | ((uint32_t)(a1 & 0xFF) << 8) |
                    ((uint32_t)(a2 & 0xFF) << 16) | ((uint32_t)(a3 & 0xFF) << 24);
        }
        sum += __shfl_down(sum, 32);
        sum += __shfl_down(sum, 16);
        sum += __shfl_down(sum, 8);
        sum += __shfl_down(sum, 4);
        sum += __shfl_down(sum, 2);
        sum += __shfl_down(sum, 1);
        __shared__ int red[4];
        if ((threadIdx.x & 63) == 0) red[threadIdx.x >> 6] = sum;
        __syncthreads();
        if (threadIdx.x == 0) rowsum[row] = red[0] + red[1] + red[2] + red[3];
    } else {
        int wrow = row - M;
        const int4* wr = (const int4*)(w + (long)wrow * K);
        uint32_t* wo = (uint32_t*)(wsq + (long)wrow * K);
        for (int i = threadIdx.x; i < n4; i += 256) {
            int4 v = wr[i];
            int a0 = v.x - 128, a1 = v.y - 128, a2 = v.z - 128, a3 = v.w - 128;
            wo[i] = (uint32_t)(a0 & 0xFF) | ((uint32_t)(a1 & 0xFF) << 8) |
                    ((uint32_t)(a2 & 0xFF) << 16) | ((uint32_t)(a3 & 0xFF) << 24);
        }
    }
}

// ---------------- main GEMM: 256x256 tile, BK=128 int8, 16x16x64 MFMA ----------------
// R11: SINGLE-buffered 64 KiB LDS -> 2 blocks/CU (was 1 at 128 KiB). Cross-block
//      TLP fills the intra-block LDS/barrier windows that 7 schedule probes
//      (R4-R10, all ~41% MfmaUtil) could not overlap intra-block (m114 mechanism).
//      Per K-tile per block: [24 reads; LGKM0 after 16; MFMA32(0); reads af4-7;
//      LGKM0; BAR(all reads retired); STAGE t+1 into same buffer; MFMA32(4)
//      covers HBM latency; VM0; BAR]. Addressing/swizzle byte-identical to R2
//      (proven 0 conflicts). Live frags capped at 16 v4i (R10 storage reuse).

#define BAR  __builtin_amdgcn_s_barrier()
#define LGKM0 asm volatile("s_waitcnt lgkmcnt(0)" ::: "memory")
#define VM0  asm volatile("s_waitcnt vmcnt(0)" ::: "memory")
#define PRIO1 __builtin_amdgcn_s_setprio(1)
#define PRIO0 __builtin_amdgcn_s_setprio(0)

// stage a 128-row half of A (opofs 0) or B (opofs 32768) for K-tile `tile`
#define STAGE(gbase, opofs, half, tile) do {                                          \
    int t_ = (tile); if (t_ >= NT) t_ = NT - 1;  /* tail: refetch L2-hot tile */      \
    const signed char* src_ = (gbase) + (long)((half) * 128) * K + (long)t_ * 128;    \
    signed char* dst_ = ldsw + (opofs) + (half) * 16384;                              \
    __builtin_amdgcn_global_load_lds(AS_GLOBAL(src_), AS_LDS(dst_), 16, 0, 0);        \
    __builtin_amdgcn_global_load_lds(AS_GLOBAL(src_ + 64L * K), AS_LDS(dst_ + 8192), 16, 0, 0); \
  } while (0)

// afs[s][ks] holds A-frag for acc row (mb + s); storage reused across halves.
#define READ_AS(s, mi) do {                                                           \
    afs[s][0] = *(const v4i*)(lds + aoff0 + (mi) * 2048);                             \
    afs[s][1] = *(const v4i*)(lds + aoff1 + (mi) * 2048); } while (0)
#define READ_B(ni) do {                                                               \
    bf[ni][0] = *(const v4i*)(lds + boff0 + (ni) * 2048);                             \
    bf[ni][1] = *(const v4i*)(lds + boff1 + (ni) * 2048); } while (0)

#define M1(s, mi, ni, ks)                                                              \
    acc[mi][ni] = __builtin_amdgcn_mfma_i32_16x16x64_i8(afs[s][ks], bf[ni][ks], acc[mi][ni], 0, 0, 0);

// 32 MFMA for acc rows mb..mb+3 x all 4 ni: ks-outer (16 independent, then 16).
#define MFMA32(mb) do {                                                                \
    M1(0, mb + 0, 0, 0) M1(0, mb + 0, 1, 0) M1(1, mb + 1, 0, 0) M1(1, mb + 1, 1, 0)   \
    M1(2, mb + 2, 0, 0) M1(2, mb + 2, 1, 0) M1(3, mb + 3, 0, 0) M1(3, mb + 3, 1, 0)   \
    M1(0, mb + 0, 2, 0) M1(0, mb + 0, 3, 0) M1(1, mb + 1, 2, 0) M1(1, mb + 1, 3, 0)   \
    M1(2, mb + 2, 2, 0) M1(2, mb + 2, 3, 0) M1(3, mb + 3, 2, 0) M1(3, mb + 3, 3, 0)   \
    M1(0, mb + 0, 0, 1) M1(0, mb + 0, 1, 1) M1(1, mb + 1, 0, 1) M1(1, mb + 1, 1, 1)   \
    M1(2, mb + 2, 0, 1) M1(2, mb + 2, 1, 1) M1(3, mb + 3, 0, 1) M1(3, mb + 3, 1, 1)   \
    M1(0, mb + 0, 2, 1) M1(0, mb + 0, 3, 1) M1(1, mb + 1, 2, 1) M1(1, mb + 1, 3, 1)   \
    M1(2, mb + 2, 2, 1) M1(2, mb + 2, 3, 1) M1(3, mb + 3, 2, 1) M1(3, mb + 3, 3, 1)   \
  } while (0)

__global__ __launch_bounds__(512, 4) void gemm_i8_sb(
    const signed char* __restrict__ A,   // xs [M,K]
    const signed char* __restrict__ B,   // ws [N,K]
    const int* __restrict__ rowsum, const float* __restrict__ wscale,
    const int* __restrict__ wzp, const float* __restrict__ bias,
    const float* __restrict__ iscale, float* __restrict__ C,
    int M, int N, int K) {
  __shared__ signed char lds[65536];   // A: 0..32767, B: 32768..65535 (single buffer)
  const int tid = threadIdx.x;
  const int w = tid >> 6, l = tid & 63;
  const int wm = w >> 2, wn = w & 3;
  const int fr = l & 15, fq = l >> 4;

  int nwg = gridDim.x, bid = blockIdx.x;
  if ((nwg & 7) == 0) { int cpx = nwg >> 3; bid = (bid & 7) * cpx + (bid >> 3); }
  const int ntiles = N >> 8;
  const int mt = bid / ntiles, nt = bid - mt * ntiles;
  const long brow = (long)mt << 8, bcol = (long)nt << 8;

  const int NT = K >> 7;      // K-tiles of 128 bytes

  // staging lane constants (unchanged from R2)
  const int srow = w * 8 + (l >> 3);
  const int schunk = ((l & 7) ^ (l >> 3)) << 4;
  const signed char* gA = A + (brow + srow) * (long)K + schunk;
  const signed char* gB = B + (bcol + srow) * (long)K + schunk;
  signed char* ldsw = lds + w * 1024;   // wave-uniform LDS dest component

  // fragment read offsets (swizzled chunk = (ks*4+fq) ^ (fr&7))
  const int axor = fr & 7;
  const int aoff0 = (wm * 128 + fr) * 128 + ((fq ^ axor) << 4);
  const int aoff1 = (wm * 128 + fr) * 128 + (((4 + fq) ^ axor) << 4);
  const int boff0 = 32768 + (wn * 64 + fr) * 128 + ((fq ^ axor) << 4);
  const int boff1 = 32768 + (wn * 64 + fr) * 128 + (((4 + fq) ^ axor) << 4);

  v4i acc[8][4] = {};
  v4i afs[4][2], bf[4][2];   // 16 live v4i fragments max

  // prologue: stage K-tile 0, full drain
  STAGE(gA, 0, 0, 0); STAGE(gA, 0, 1, 0);
  STAGE(gB, 32768, 0, 0); STAGE(gB, 32768, 1, 0);
  VM0; BAR;

  for (int t = 0; t < NT; ++t) {
    // all 16 reads for acc rows 0-3 + all B
    READ_AS(0, 0); READ_AS(1, 1); READ_AS(2, 2); READ_AS(3, 3);
    READ_B(0); READ_B(1); READ_B(2); READ_B(3);
    LGKM0;
    PRIO1; MFMA32(0); PRIO0;
    // remaining 8 reads (af4-7) into reused storage
    READ_AS(0, 4); READ_AS(1, 5); READ_AS(2, 6); READ_AS(3, 7);
    LGKM0; BAR;                          // every wave's 24 reads retired -> buffer free
    // stage K-tile t+1 into the same buffer; its HBM latency hides under MFMA32(4)
    STAGE(gA, 0, 0, t + 1); STAGE(gA, 0, 1, t + 1);
    STAGE(gB, 32768, 0, t + 1); STAGE(gB, 32768, 1, t + 1);
    PRIO1; MFMA32(4); PRIO0;
    VM0; BAR;                            // staged data visible for next iteration
  }

  // epilogue: out = (acc + (128 - wzp[n]) * rowsum[m]) * (iscale * wscale[n]) + bias[n]
  const float is = iscale[0];
  int rs[8][4];
#pragma unroll
  for (int mi = 0; mi < 8; ++mi)
#pragma unroll
    for (int j = 0; j < 4; ++j)
      rs[mi][j] = rowsum[(int)brow + wm * 128 + mi * 16 + fq * 4 + j];
#pragma unroll
  for (int ni = 0; ni < 4; ++ni) {
    const int col = (int)bcol + wn * 64 + ni * 16 + fr;
    const float sc = is * wscale[col];
    const int zpc = 128 - wzp[col];
    const float bi = bias[col];
#pragma unroll
    for (int mi = 0; mi < 8; ++mi) {
      const int row0 = (int)brow + wm * 128 + mi * 16 + fq * 4;
#pragma unroll
      for (int j = 0; j < 4; ++j) {
        const int v = acc[mi][ni][j] + zpc * rs[mi][j];
        C[(long)(row0 + j) * N + col] = (float)v * sc + bi;
      }
    }
  }
}

extern "C" void kernel_launch(void* const* d_in, const int* in_sizes, int n_in,
                              void* d_out, int out_size, void* d_ws, size_t ws_size,
                              hipStream_t stream) {
    const int* x_q = (const int*)d_in[0];
    const int* w_q = (const int*)d_in[1];
    const float* wscale = (const float*)d_in[2];
    const int* wzp = (const int*)d_in[3];
    const float* bias = (const float*)d_in[4];
    const float* iscale = (const float*)d_in[5];
    const int* izp = (const int*)d_in[6];

    int N = in_sizes[2];            // weight_scale has N elements
    int K = in_sizes[1] / N;        // weight is [N, K]
    int M = in_sizes[0] / K;        // x is [M, K]

    signed char* xs = (signed char*)d_ws;
    signed char* wsq = xs + (size_t)M * K;
    int* rowsum = (int*)(wsq + (size_t)N * K);

    prep_kernel<<<M + N, 256, 0, stream>>>(x_q, w_q, izp, xs, wsq, rowsum, M, K);

    int grid = (M / 256) * (N / 256);
    gemm_i8_sb<<<grid, 512, 0, stream>>>(xs, wsq, rowsum, wscale, wzp, bias, iscale,
                                         (float*)d_out, M, N, K);
}

// Round 12
// 199.260 us; speedup vs baseline: 6.4094x; 6.4094x over previous
//
#include <hip/hip_runtime.h>
#include <hip/hip_bf16.h>
#include <stdint.h>

typedef int v4i __attribute__((ext_vector_type(4)));

#define AS_GLOBAL(p) ((const __attribute__((address_space(1))) void*)(p))
#define AS_LDS(p)    ((__attribute__((address_space(3))) void*)(p))

// ---------------- merged prepass: rows [0,M) = x - izp (+rowsum); rows [M, M+N) = w - 128
__global__ __launch_bounds__(256) void prep_kernel(const int* __restrict__ x,
                                                   const int* __restrict__ w,
                                                   const int* __restrict__ izp_p,
                                                   signed char* __restrict__ xs,
                                                   signed char* __restrict__ wsq,
                                                   int* __restrict__ rowsum, int M, int K) {
    int row = blockIdx.x;
    int n4 = K >> 2;
    if (row < M) {
        int izp = izp_p[0];
        const int4* xr = (const int4*)(x + (long)row * K);
        uint32_t* xo = (uint32_t*)(xs + (long)row * K);
        int sum = 0;
        for (int i = threadIdx.x; i < n4; i += 256) {
            int4 v = xr[i];
            int a0 = v.x - izp, a1 = v.y - izp, a2 = v.z - izp, a3 = v.w - izp;
            sum += a0 + a1 + a2 + a3;
            xo[i] = (uint32_t)(a0 & 0xFF) | ((uint32_t)(a1 & 0xFF) << 8) |
                    ((uint32_t)(a2 & 0xFF) << 16) | ((uint32_t)(a3 & 0xFF) << 24);
        }
        sum += __shfl_down(sum, 32);
        sum += __shfl_down(sum, 16);
        sum += __shfl_down(sum, 8);
        sum += __shfl_down(sum, 4);
        sum += __shfl_down(sum, 2);
        sum += __shfl_down(sum, 1);
        __shared__ int red[4];
        if ((threadIdx.x & 63) == 0) red[threadIdx.x >> 6] = sum;
        __syncthreads();
        if (threadIdx.x == 0) rowsum[row] = red[0] + red[1] + red[2] + red[3];
    } else {
        int wrow = row - M;
        const int4* wr = (const int4*)(w + (long)wrow * K);
        uint32_t* wo = (uint32_t*)(wsq + (long)wrow * K);
        for (int i = threadIdx.x; i < n4; i += 256) {
            int4 v = wr[i];
            int a0 = v.x - 128, a1 = v.y - 128, a2 = v.z - 128, a3 = v.w - 128;
            wo[i] = (uint32_t)(a0 & 0xFF) | ((uint32_t)(a1 & 0xFF) << 8) |
                    ((uint32_t)(a2 & 0xFF) << 16) | ((uint32_t)(a3 & 0xFF) << 24);
        }
    }
}

// ---------------- main GEMM: 128x128 tile, BK=128 int8, 16x16x64 MFMA ----------------
// R12: 4-wave (256-thread) blocks, single-buffered 32 KiB LDS, __launch_bounds__(256,3)
//      -> 3 blocks/CU (12 waves). Cross-BLOCK TLP fills each block's LDS/stage/barrier
//      windows (m114) — the overlap R4-R10 proved unreachable intra-block. R11's
//      failure was the register cap at 8-wave 256² (acc alone = 128); here
//      acc[4][4]=64 + ~16 frag v4i + addressing ≈ 150-165 regs fits the 170 cap.
//      Addressing/swizzle formulas identical to the proven 0-conflict R2 scheme.
// Per wave: output 64x64 = acc[4][4]; per K-tile 16 ds_read_b128 + 8 gload_lds + 32 MFMA.

#define BAR  __builtin_amdgcn_s_barrier()
#define LGKM0 asm volatile("s_waitcnt lgkmcnt(0)" ::: "memory")
#define VM0  asm volatile("s_waitcnt vmcnt(0)" ::: "memory")
#define PRIO1 __builtin_amdgcn_s_setprio(1)
#define PRIO0 __builtin_amdgcn_s_setprio(0)

// stage 32 rows (4 gloads x 8 rows... one gload covers 8 rows): wave w stages rows
// {g*32 + w*8 + (l>>3)} for g=0..3 of operand at opofs (A=0, B=16384).
#define STAGE_OP(gbase, opofs, tile) do {                                             \
    int t_ = (tile); if (t_ >= NT) t_ = NT - 1;  /* tail: refetch L2-hot tile */      \
    const signed char* s0_ = (gbase) + (long)t_ * 128;                                \
    signed char* d0_ = ldsw + (opofs);                                                \
    __builtin_amdgcn_global_load_lds(AS_GLOBAL(s0_),            AS_LDS(d0_),         16, 0, 0); \
    __builtin_amdgcn_global_load_lds(AS_GLOBAL(s0_ + 32L * K),  AS_LDS(d0_ + 4096),  16, 0, 0); \
    __builtin_amdgcn_global_load_lds(AS_GLOBAL(s0_ + 64L * K),  AS_LDS(d0_ + 8192),  16, 0, 0); \
    __builtin_amdgcn_global_load_lds(AS_GLOBAL(s0_ + 96L * K),  AS_LDS(d0_ + 12288), 16, 0, 0); \
  } while (0)

#define READ_A(mi) do {                                                               \
    af[mi][0] = *(const v4i*)(lds + aoff0 + (mi) * 2048);                             \
    af[mi][1] = *(const v4i*)(lds + aoff1 + (mi) * 2048); } while (0)
#define READ_B(ni) do {                                                               \
    bf[ni][0] = *(const v4i*)(lds + boff0 + (ni) * 2048);                             \
    bf[ni][1] = *(const v4i*)(lds + boff1 + (ni) * 2048); } while (0)

#define M1(mi, ni, ks)                                                                 \
    acc[mi][ni] = __builtin_amdgcn_mfma_i32_16x16x64_i8(af[mi][ks], bf[ni][ks], acc[mi][ni], 0, 0, 0);

// 32 MFMA, ks-outer (16 independent, then 16).
#define MFMA32 do {                                                                    \
    M1(0, 0, 0) M1(0, 1, 0) M1(1, 0, 0) M1(1, 1, 0)                                    \
    M1(2, 0, 0) M1(2, 1, 0) M1(3, 0, 0) M1(3, 1, 0)                                    \
    M1(0, 2, 0) M1(0, 3, 0) M1(1, 2, 0) M1(1, 3, 0)                                    \
    M1(2, 2, 0) M1(2, 3, 0) M1(3, 2, 0) M1(3, 3, 0)                                    \
    M1(0, 0, 1) M1(0, 1, 1) M1(1, 0, 1) M1(1, 1, 1)                                    \
    M1(2, 0, 1) M1(2, 1, 1) M1(3, 0, 1) M1(3, 1, 1)                                    \
    M1(0, 2, 1) M1(0, 3, 1) M1(1, 2, 1) M1(1, 3, 1)                                    \
    M1(2, 2, 1) M1(2, 3, 1) M1(3, 2, 1) M1(3, 3, 1)                                    \
  } while (0)

__global__ __launch_bounds__(256, 3) void gemm_i8_4w(
    const signed char* __restrict__ A,   // xs [M,K]
    const signed char* __restrict__ B,   // ws [N,K]
    const int* __restrict__ rowsum, const float* __restrict__ wscale,
    const int* __restrict__ wzp, const float* __restrict__ bias,
    const float* __restrict__ iscale, float* __restrict__ C,
    int M, int N, int K) {
  __shared__ signed char lds[32768];   // A: 0..16383, B: 16384..32767 (single buffer)
  const int tid = threadIdx.x;
  const int w = tid >> 6, l = tid & 63;
  const int wm = w >> 1, wn = w & 1;
  const int fr = l & 15, fq = l >> 4;

  int nwg = gridDim.x, bid = blockIdx.x;
  if ((nwg & 7) == 0) { int cpx = nwg >> 3; bid = (bid & 7) * cpx + (bid >> 3); }
  const int ntiles = N >> 7;
  const int mt = bid / ntiles, nt = bid - mt * ntiles;
  const long brow = (long)mt << 7, bcol = (long)nt << 7;

  const int NT = K >> 7;      // K-tiles of 128 bytes

  // staging lane constants: wave w, gload g -> rows g*32 + w*8 + (l>>3);
  // source chunk pre-swizzled: stored[row][c] = G[row][c ^ (row&7)], row&7 = l>>3.
  const int srow = w * 8 + (l >> 3);
  const int schunk = ((l & 7) ^ (l >> 3)) << 4;
  const signed char* gA = A + (brow + srow) * (long)K + schunk;
  const signed char* gB = B + (bcol + srow) * (long)K + schunk;
  signed char* ldsw = lds + w * 1024;   // wave-uniform LDS dest component

  // fragment read offsets (swizzled chunk = (ks*4+fq) ^ (fr&7)) — proven 0-conflict
  const int axor = fr & 7;
  const int aoff0 = (wm * 64 + fr) * 128 + ((fq ^ axor) << 4);
  const int aoff1 = (wm * 64 + fr) * 128 + (((4 + fq) ^ axor) << 4);
  const int boff0 = 16384 + (wn * 64 + fr) * 128 + ((fq ^ axor) << 4);
  const int boff1 = 16384 + (wn * 64 + fr) * 128 + (((4 + fq) ^ axor) << 4);

  v4i acc[4][4] = {};
  v4i af[4][2], bf[4][2];   // 16 live v4i fragments

  // prologue: stage K-tile 0, full drain
  STAGE_OP(gA, 0, 0);
  STAGE_OP(gB, 16384, 0);
  VM0; BAR;

  for (int t = 0; t < NT; ++t) {
    READ_A(0); READ_A(1); READ_A(2); READ_A(3);
    READ_B(0); READ_B(1); READ_B(2); READ_B(3);
    LGKM0; BAR;                          // all 16 reads retired -> buffer free
    STAGE_OP(gA, 0, t + 1);              // stage t+1 into same buffer; latency
    STAGE_OP(gB, 16384, t + 1);          //   hides under MFMA + other blocks
    PRIO1; MFMA32; PRIO0;
    VM0; BAR;                            // staged data visible for next iteration
  }

  // epilogue: out = (acc + (128 - wzp[n]) * rowsum[m]) * (iscale * wscale[n]) + bias[n]
  const float is = iscale[0];
  int rs[4][4];
#pragma unroll
  for (int mi = 0; mi < 4; ++mi)
#pragma unroll
    for (int j = 0; j < 4; ++j)
      rs[mi][j] = rowsum[(int)brow + wm * 64 + mi * 16 + fq * 4 + j];
#pragma unroll
  for (int ni = 0; ni < 4; ++ni) {
    const int col = (int)bcol + wn * 64 + ni * 16 + fr;
    const float sc = is * wscale[col];
    const int zpc = 128 - wzp[col];
    const float bi = bias[col];
#pragma unroll
    for (int mi = 0; mi < 4; ++mi) {
      const int row0 = (int)brow + wm * 64 + mi * 16 + fq * 4;
#pragma unroll
      for (int j = 0; j < 4; ++j) {
        const int v = acc[mi][ni][j] + zpc * rs[mi][j];
        C[(long)(row0 + j) * N + col] = (float)v * sc + bi;
      }
    }
  }
}

extern "C" void kernel_launch(void* const* d_in, const int* in_sizes, int n_in,
                              void* d_out, int out_size, void* d_ws, size_t ws_size,
                              hipStream_t stream) {
    const int* x_q = (const int*)d_in[0];
    const int* w_q = (const int*)d_in[1];
    const float* wscale = (const float*)d_in[2];
    const int* wzp = (const int*)d_in[3];
    const float* bias = (const float*)d_in[4];
    const float* iscale = (const float*)d_in[5];
    const int* izp = (const int*)d_in[6];

    int N = in_sizes[2];            // weight_scale has N elements
    int K = in_sizes[1] / N;        // weight is [N, K]
    int M = in_sizes[0] / K;        // x is [M, K]

    signed char* xs = (signed char*)d_ws;
    signed char* wsq = xs + (size_t)M * K;
    int* rowsum = (int*)(wsq + (size_t)N * K);

    prep_kernel<<<M + N, 256, 0, stream>>>(x_q, w_q, izp, xs, wsq, rowsum, M, K);

    int grid = (M / 128) * (N / 128);   // 2048 blocks
    gemm_i8_4w<<<grid, 256, 0, stream>>>(xs, wsq, rowsum, wscale, wzp, bias, iscale,
                                         (float*)d_out, M, N, K);
}

// Round 13
// 191.998 us; speedup vs baseline: 6.6519x; 1.0378x over previous
//
#include <hip/hip_runtime.h>
#include <hip/hip_bf16.h>
#include <stdint.h>

typedef int v4i __attribute__((ext_vector_type(4)));

#define AS_GLOBAL(p) ((const __attribute__((address_space(1))) void*)(p))
#define AS_LDS(p)    ((__attribute__((address_space(3))) void*)(p))

// ---------------- merged prepass: rows [0,M) = x - izp (+rowsum); rows [M, M+N) = w - 128
__global__ __launch_bounds__(256) void prep_kernel(const int* __restrict__ x,
                                                   const int* __restrict__ w,
                                                   const int* __restrict__ izp_p,
                                                   signed char* __restrict__ xs,
                                                   signed char* __restrict__ wsq,
                                                   int* __restrict__ rowsum, int M, int K) {
    int row = blockIdx.x;
    int n4 = K >> 2;
    if (row < M) {
        int izp = izp_p[0];
        const int4* xr = (const int4*)(x + (long)row * K);
        uint32_t* xo = (uint32_t*)(xs + (long)row * K);
        int sum = 0;
        for (int i = threadIdx.x; i < n4; i += 256) {
            int4 v = xr[i];
            int a0 = v.x - izp, a1 = v.y - izp, a2 = v.z - izp, a3 = v.w - izp;
            sum += a0 + a1 + a2 + a3;
            xo[i] = (uint32_t)(a0 & 0xFF) | ((uint32_t)(a1 & 0xFF) << 8) |
                    ((uint32_t)(a2 & 0xFF) << 16) | ((uint32_t)(a3 & 0xFF) << 24);
        }
        sum += __shfl_down(sum, 32);
        sum += __shfl_down(sum, 16);
        sum += __shfl_down(sum, 8);
        sum += __shfl_down(sum, 4);
        sum += __shfl_down(sum, 2);
        sum += __shfl_down(sum, 1);
        __shared__ int red[4];
        if ((threadIdx.x & 63) == 0) red[threadIdx.x >> 6] = sum;
        __syncthreads();
        if (threadIdx.x == 0) rowsum[row] = red[0] + red[1] + red[2] + red[3];
    } else {
        int wrow = row - M;
        const int4* wr = (const int4*)(w + (long)wrow * K);
        uint32_t* wo = (uint32_t*)(wsq + (long)wrow * K);
        for (int i = threadIdx.x; i < n4; i += 256) {
            int4 v = wr[i];
            int a0 = v.x - 128, a1 = v.y - 128, a2 = v.z - 128, a3 = v.w - 128;
            wo[i] = (uint32_t)(a0 & 0xFF) | ((uint32_t)(a1 & 0xFF) << 8) |
                    ((uint32_t)(a2 & 0xFF) << 16) | ((uint32_t)(a3 & 0xFF) << 24);
        }
    }
}

// ---------------- main GEMM: 256x256 tile, BK=64 int8, 4-deep LDS pipeline ----------------
// R13: NEVER-DRAIN pipeline (m201's T3+T4 in true form). 4 buffers x 32KB; iter t
//      reads buf t&3, stages tile t+3 into buf (t+3)&3, vmcnt(8) keeps 2 tiles in
//      flight (issue->wait distance ~3 K-tiles ~4200cyc >> 900cyc HBM miss).
//      BK=64: every acc touched once/tile -> all 32 MFMAs independent; 1 barrier,
//      one region {reads | stage | MFMA} per tile. Hazards: iter t+1 stages buf
//      (t+4)&3 = t&3, whose readers (this iter) retire at this iter's LGKM0+BAR.
//      VM8 at iter end => tile t+1 resident before its reads. Tail stages clamp
//      to NT-1 (harmless refetch keeps vmcnt counts exact).
// Swizzle (BK=64, 64B rows, 4 chunks): store c^((row>>1)&3) via pre-swizzled
//      source; read chunk fq^((fr>>1)&3) -> 2 lanes/bank-group per 16-lane phase.

#define BAR  __builtin_amdgcn_s_barrier()
#define LGKM0 asm volatile("s_waitcnt lgkmcnt(0)" ::: "memory")
#define VM8  asm volatile("s_waitcnt vmcnt(8)" ::: "memory")
#define VM0  asm volatile("s_waitcnt vmcnt(0)" ::: "memory")
#define PRIO1 __builtin_amdgcn_s_setprio(1)
#define PRIO0 __builtin_amdgcn_s_setprio(0)

// stage K-tile `tile` into buffer bb: 4 gloads/wave (A g0,g1; B g0,g1), 1KB each.
#define STAGE(bb, tile) do {                                                          \
    int t_ = (tile); if (t_ >= NT) t_ = NT - 1;                                       \
    long ko_ = (long)t_ * 64;                                                         \
    signed char* lb_ = lds + (bb) * 32768 + w * 2048;                                 \
    __builtin_amdgcn_global_load_lds(AS_GLOBAL(gA0 + ko_), AS_LDS(lb_),         16, 0, 0); \
    __builtin_amdgcn_global_load_lds(AS_GLOBAL(gA1 + ko_), AS_LDS(lb_ + 1024),  16, 0, 0); \
    __builtin_amdgcn_global_load_lds(AS_GLOBAL(gB0 + ko_), AS_LDS(lb_ + 16384), 16, 0, 0); \
    __builtin_amdgcn_global_load_lds(AS_GLOBAL(gB1 + ko_), AS_LDS(lb_ + 17408), 16, 0, 0); \
  } while (0)

#define M1(mi, ni)                                                                     \
    acc[mi][ni] = __builtin_amdgcn_mfma_i32_16x16x64_i8(af[mi], bf[ni], acc[mi][ni], 0, 0, 0);

__global__ __launch_bounds__(512, 2) void gemm_i8_p4(
    const signed char* __restrict__ A,   // xs [M,K]
    const signed char* __restrict__ B,   // ws [N,K]
    const int* __restrict__ rowsum, const float* __restrict__ wscale,
    const int* __restrict__ wzp, const float* __restrict__ bias,
    const float* __restrict__ iscale, float* __restrict__ C,
    int M, int N, int K) {
  __shared__ signed char lds[131072];   // 4 x {A:16KB | B:16KB}
  const int tid = threadIdx.x;
  const int w = tid >> 6, l = tid & 63;
  const int wm = w >> 2, wn = w & 3;
  const int fr = l & 15, fq = l >> 4;

  int nwg = gridDim.x, bid = blockIdx.x;
  if ((nwg & 7) == 0) { int cpx = nwg >> 3; bid = (bid & 7) * cpx + (bid >> 3); }
  const int ntiles = N >> 8;
  const int mt = bid / ntiles, nt = bid - mt * ntiles;
  const long brow = (long)mt << 8, bcol = (long)nt << 8;

  const int NT = K >> 6;      // K-tiles of 64 bytes

  // staging lane constants: gload g of operand covers rows (w*2+g)*16..+16;
  // lane l -> row +(l>>2), source chunk (l&3) ^ ((l>>3)&3) (pre-swizzle).
  const int sr = l >> 2;
  const int schunk = ((l & 3) ^ ((l >> 3) & 3)) << 4;
  const signed char* gA0 = A + (brow + (w * 2 + 0) * 16 + sr) * (long)K + schunk;
  const signed char* gA1 = A + (brow + (w * 2 + 1) * 16 + sr) * (long)K + schunk;
  const signed char* gB0 = B + (bcol + (w * 2 + 0) * 16 + sr) * (long)K + schunk;
  const signed char* gB1 = B + (bcol + (w * 2 + 1) * 16 + sr) * (long)K + schunk;

  // fragment read offsets: row*64 + (fq ^ ((fr>>1)&3))*16; mi/ni step = 16*64 = 1024
  const int rdc = (fq ^ ((fr >> 1) & 3)) << 4;
  const int aoffc = (wm * 128 + fr) * 64 + rdc;
  const int boffc = 16384 + (wn * 64 + fr) * 64 + rdc;

  v4i acc[8][4] = {};
  v4i af[8], bf[4];

  // prologue: stage tiles 0,1,2 (12 gloads/wave); wait first 4 -> tile 0 resident.
  STAGE(0, 0); STAGE(1, 1); STAGE(2, 2);
  VM8; BAR;

  for (int t = 0; t < NT; ++t) {
    const int bufo = (t & 3) << 15;
#pragma unroll
    for (int mi = 0; mi < 8; ++mi) af[mi] = *(const v4i*)(lds + bufo + aoffc + mi * 1024);
#pragma unroll
    for (int ni = 0; ni < 4; ++ni) bf[ni] = *(const v4i*)(lds + bufo + boffc + ni * 1024);
    STAGE((t + 3) & 3, t + 3);
    PRIO1;
    M1(0, 0) M1(0, 1) M1(0, 2) M1(0, 3)
    M1(1, 0) M1(1, 1) M1(1, 2) M1(1, 3)
    M1(2, 0) M1(2, 1) M1(2, 2) M1(2, 3)
    M1(3, 0) M1(3, 1) M1(3, 2) M1(3, 3)
    M1(4, 0) M1(4, 1) M1(4, 2) M1(4, 3)
    M1(5, 0) M1(5, 1) M1(5, 2) M1(5, 3)
    M1(6, 0) M1(6, 1) M1(6, 2) M1(6, 3)
    M1(7, 0) M1(7, 1) M1(7, 2) M1(7, 3)
    PRIO0;
    LGKM0;   // all 12 reads retired (free: MFMAs consumed them) -> buf t&3 safe to overwrite next iter
    VM8;     // tile t+1 resident (its 4 gloads are the oldest of 12 outstanding)
    BAR;
  }

  // epilogue: out = (acc + (128 - wzp[n]) * rowsum[m]) * (iscale * wscale[n]) + bias[n]
  const float is = iscale[0];
  int rs[8][4];
#pragma unroll
  for (int mi = 0; mi < 8; ++mi)
#pragma unroll
    for (int j = 0; j < 4; ++j)
      rs[mi][j] = rowsum[(int)brow + wm * 128 + mi * 16 + fq * 4 + j];
#pragma unroll
  for (int ni = 0; ni < 4; ++ni) {
    const int col = (int)bcol + wn * 64 + ni * 16 + fr;
    const float sc = is * wscale[col];
    const int zpc = 128 - wzp[col];
    const float bi = bias[col];
#pragma unroll
    for (int mi = 0; mi < 8; ++mi) {
      const int row0 = (int)brow + wm * 128 + mi * 16 + fq * 4;
#pragma unroll
      for (int j = 0; j < 4; ++j) {
        const int v = acc[mi][ni][j] + zpc * rs[mi][j];
        C[(long)(row0 + j) * N + col] = (float)v * sc + bi;
      }
    }
  }
}

extern "C" void kernel_launch(void* const* d_in, const int* in_sizes, int n_in,
                              void* d_out, int out_size, void* d_ws, size_t ws_size,
                              hipStream_t stream) {
    const int* x_q = (const int*)d_in[0];
    const int* w_q = (const int*)d_in[1];
    const float* wscale = (const float*)d_in[2];
    const int* wzp = (const int*)d_in[3];
    const float* bias = (const float*)d_in[4];
    const float* iscale = (const float*)d_in[5];
    const int* izp = (const int*)d_in[6];

    int N = in_sizes[2];            // weight_scale has N elements
    int K = in_sizes[1] / N;        // weight is [N, K]
    int M = in_sizes[0] / K;        // x is [M, K]

    signed char* xs = (signed char*)d_ws;
    signed char* wsq = xs + (size_t)M * K;
    int* rowsum = (int*)(wsq + (size_t)N * K);

    prep_kernel<<<M + N, 256, 0, stream>>>(x_q, w_q, izp, xs, wsq, rowsum, M, K);

    int grid = (M / 256) * (N / 256);   // 512 blocks
    gemm_i8_p4<<<grid, 512, 0, stream>>>(xs, wsq, rowsum, wscale, wzp, bias, iscale,
                                         (float*)d_out, M, N, K);
}